// Round 2
// baseline (884.872 us; speedup 1.0000x reference)
//
#include <hip/hip_runtime.h>
#include <math.h>

#define QTOT 65536
#define CC 64
#define DD 512
#define QB 64            /* queries per block */
#define BLK 256
#define NIT 16           /* k-loop iterations; 16 k-values per half per iter */
#define LBS 20           /* staging row stride (words): 80 B, conflict-free b128 */
#define EXS 68           /* exchange/out tile row stride (words): 272 B */

/* ws float layout (same as R1):
   [0] sum c_f  [1] sum c_r  [2] n_r  [3] masked g_f  [4] masked g_r
   [16..144) proto norms (rgb 64 then flow 64)
   [256..256+65536) g_f   [256+65536 ..) g_r  */
enum { WS_SCF = 0, WS_SCR = 1, WS_CNT = 2, WS_MGF = 3, WS_MGR = 4,
       WS_NP = 16, WS_GF = 256, WS_GR = 256 + QTOT };

__global__ __launch_bounds__(64) void k0_norms_zero(
    const float* __restrict__ ctx_r, const float* __restrict__ ctx_f,
    float* ws) {
  const int b = blockIdx.x;        /* 0..127 = modality*64 + proto */
  const int lane = threadIdx.x;
  const float* base = (b < CC) ? ctx_r : ctx_f;
  const int proto = b & (CC - 1);
  const float4* row = (const float4*)(base + (size_t)proto * DD);
  float s = 0.f;
#pragma unroll
  for (int i = 0; i < DD / 4 / 64; ++i) {
    float4 v = row[lane + i * 64];
    s = fmaf(v.x, v.x, s); s = fmaf(v.y, v.y, s);
    s = fmaf(v.z, v.z, s); s = fmaf(v.w, v.w, s);
  }
#pragma unroll
  for (int off = 32; off > 0; off >>= 1) s += __shfl_xor(s, off);
  if (lane == 0) ws[WS_NP + b] = s;
  if (b == 0 && lane < 16) ws[lane] = 0.f;
}

/* K1: wave = (modality, D-half), lane = query. 64 queries/block, grid 1024.
   Protos wave-uniform -> SGPR broadcast FMA. 4 waves/SIMD for TLP. */
__global__ __launch_bounds__(BLK, 4) void k1_main(
    const float* __restrict__ ctx_r, const float* __restrict__ ctx_f,
    const float* __restrict__ tgt_r, const float* __restrict__ tgt_f,
    float* ws, float* __restrict__ out) {
  __shared__ __align__(16) float arena[2 * QB * EXS];   /* 34816 B, phase-reused */
  __shared__ float xch[2][4][QB];                       /* [mod][{min,S,conf,ent}][q] */

  const int tid = threadIdx.x;
  const int w = tid >> 6;          /* wave: (m<<1)|h */
  const int mw = w >> 1, hw = w & 1;
  const int lane = tid & 63;
  const int q0 = blockIdx.x * QB;

  float acc[CC];
#pragma unroll
  for (int c = 0; c < CC; ++c) acc[c] = 0.f;
  float nq = 0.f;

  /* ---- k-loop: stage 4 (mod,half) 64x16 tiles per iter, SGPR-proto FMA ---- */
  float4 pre[4];
#pragma unroll
  for (int i = 0; i < 4; ++i) {
    const int m = i >> 1, row = ((i & 1) << 5) + (tid >> 3);
    const int h = (tid >> 2) & 1, p = tid & 3;
    const float4* src = (const float4*)(m ? tgt_f : tgt_r);
    pre[i] = src[(size_t)(q0 + row) * 128 + h * 64 + p];
  }

  const float* Pm = (mw ? ctx_f : ctx_r) + hw * 256;

#pragma unroll 1
  for (int it = 0; it < NIT; ++it) {
    __syncthreads();
#pragma unroll
    for (int i = 0; i < 4; ++i) {
      const int m = i >> 1, row = ((i & 1) << 5) + (tid >> 3);
      const int h = (tid >> 2) & 1, p = tid & 3;
      const int t = ((m << 1) + h) * 64 + row;
      *(float4*)&arena[t * LBS + p * 4] = pre[i];
    }
    __syncthreads();
    if (it + 1 < NIT) {
#pragma unroll
      for (int i = 0; i < 4; ++i) {
        const int m = i >> 1, row = ((i & 1) << 5) + (tid >> 3);
        const int h = (tid >> 2) & 1, p = tid & 3;
        const float4* src = (const float4*)(m ? tgt_f : tgt_r);
        pre[i] = src[(size_t)(q0 + row) * 128 + h * 64 + (it + 1) * 4 + p];
      }
    }
    float q_[16];
#pragma unroll
    for (int j = 0; j < 4; ++j) {
      float4 a = *(const float4*)&arena[tid * LBS + j * 4];
      q_[4 * j] = a.x; q_[4 * j + 1] = a.y; q_[4 * j + 2] = a.z; q_[4 * j + 3] = a.w;
    }
#pragma unroll
    for (int j = 0; j < 16; ++j) nq = fmaf(q_[j], q_[j], nq);
    const float* P = Pm + it * 16;
#pragma unroll
    for (int c = 0; c < CC; ++c) {
      float a = acc[c];
#pragma unroll
      for (int j = 0; j < 16; ++j) a = fmaf(P[c * DD + j], q_[j], a);
      acc[c] = a;
    }
  }

  /* ---- combine halves via LDS (h=1 waves export, h=0 waves own epilogue) -- */
  __syncthreads();                                   /* staging dead */
  if (hw == 1) {
    const int r = (mw * QB + lane) * EXS;
#pragma unroll
    for (int c4 = 0; c4 < 16; ++c4)
      *(float4*)&arena[r + c4 * 4] = make_float4(acc[c4 * 4], acc[c4 * 4 + 1],
                                                 acc[c4 * 4 + 2], acc[c4 * 4 + 3]);
    arena[r + 64] = nq;
  }
  __syncthreads();

  float Sx = 0.f, Tx = 0.f, Mx = 0.f, conf = 0.f, ent = 0.f, invS = 0.f;
  if (hw == 0) {
    const int r = (mw * QB + lane) * EXS;
    nq += arena[r + 64];
    const float* np = ws + WS_NP + mw * CC;
    float mloc = 3.4e38f;
#pragma unroll
    for (int c4 = 0; c4 < 16; ++c4) {
      float4 v = *(const float4*)&arena[r + c4 * 4];
#pragma unroll
      for (int u = 0; u < 4; ++u) {
        const int c = c4 * 4 + u;
        float dot = acc[c] + (&v.x)[u];
        float d = sqrtf(fmaxf(nq + np[c] - 2.f * dot, 0.f));
        acc[c] = d;
        mloc = fminf(mloc, d);
      }
    }
    xch[mw][0][lane] = mloc;
  }
  __syncthreads();

  if (hw == 0) {
    const float msh = fminf(xch[0][0][lane], xch[1][0][lane]);
#pragma unroll
    for (int c = 0; c < CC; ++c) {
      float x = msh - acc[c];
      float e = __expf(x);
      acc[c] = e;                                    /* acc now holds e */
      Sx += e; Tx = fmaf(e, x, Tx); Mx = fmaxf(Mx, e);
    }
    invS = 1.f / Sx;
    conf = Mx * invS;
    ent = __logf(Sx) - Tx * invS;
    xch[mw][1][lane] = Sx;
    xch[mw][2][lane] = conf;
    xch[mw][3][lane] = ent;
  }
  __syncthreads();

  /* ---- stage p tiles (PR rows 0..63, PF rows 64..127), coalesced store ---- */
  if (hw == 0) {
    const int r = (mw * QB + lane) * EXS;
#pragma unroll
    for (int c4 = 0; c4 < 16; ++c4)
      *(float4*)&arena[r + c4 * 4] =
          make_float4(acc[c4 * 4] * invS, acc[c4 * 4 + 1] * invS,
                      acc[c4 * 4 + 2] * invS, acc[c4 * 4 + 3] * invS);
  }
  __syncthreads();

  float* out_pf = out + 2;
  float* out_pr = out + 2 + (size_t)QTOT * CC;
  float* out_po = out + 2 + (size_t)2 * QTOT * CC;
#pragma unroll
  for (int i = 0; i < 4; ++i) {                      /* PR tile -> out_pr */
    const int g = tid + 256 * i, row = g >> 4, c4 = g & 15;
    float4 v = *(const float4*)&arena[row * EXS + c4 * 4];
    *(float4*)(out_pr + (size_t)(q0 + row) * CC + c4 * 4) = v;
  }
#pragma unroll
  for (int i = 0; i < 4; ++i) {                      /* PF tile -> out_pf */
    const int g = tid + 256 * i, row = g >> 4, c4 = g & 15;
    float4 v = *(const float4*)&arena[(QB + row) * EXS + c4 * 4];
    *(float4*)(out_pf + (size_t)(q0 + row) * CC + c4 * 4) = v;
  }

  /* ---- cross-KL + fused posterior (wave0: rgb side; wave2: flow side) ---- */
  if (w == 0) {
    const float cr = conf, hr = ent, Sr = Sx;
    const float cf = xch[1][2][lane], hf = xch[1][3][lane], Sf = xch[1][1][lane];
    const float wr = cr / (cr + cf), wf = cf / (cr + cf);
    const float a = wr * Sr, b = wf * Sf;
    const float dinv = 1.f / (a + b);
    float klrf = 0.f;
#pragma unroll
    for (int c4 = 0; c4 < 16; ++c4) {
      float4 pfv = *(const float4*)&arena[(QB + lane) * EXS + c4 * 4];
#pragma unroll
      for (int u = 0; u < 4; ++u) {
        const int c = c4 * 4 + u;
        float pr = acc[c] * invS;
        klrf = fmaf(pr, __logf(pr) - (&pfv.x)[u], klrf);
        acc[c] = (a * pr + b * (&pfv.x)[u]) * dinv;  /* acc now holds po */
      }
    }
    ws[WS_GR + q0 + lane] = cr * klrf * (1.f / 64.f);
    const float maskv = (hr > hf && cr > cf) ? 1.f : 0.f;
    float scf = cf, scr = cr, scnt = maskv;
#pragma unroll
    for (int off = 32; off > 0; off >>= 1) {
      scf += __shfl_xor(scf, off);
      scr += __shfl_xor(scr, off);
      scnt += __shfl_xor(scnt, off);
    }
    if (lane == 0) {
      atomicAdd(&ws[WS_SCF], scf);
      atomicAdd(&ws[WS_SCR], scr);
      atomicAdd(&ws[WS_CNT], scnt);
    }
  } else if (w == 2) {
    const float cf = conf;
    float klfr = 0.f;
#pragma unroll
    for (int c4 = 0; c4 < 16; ++c4) {
      float4 prv = *(const float4*)&arena[lane * EXS + c4 * 4];
#pragma unroll
      for (int u = 0; u < 4; ++u) {
        const int c = c4 * 4 + u;
        float pf = acc[c] * invS;
        klfr = fmaf(pf, __logf(pf) - (&prv.x)[u], klfr);
      }
    }
    ws[WS_GF + q0 + lane] = cf * klfr * (1.f / 64.f);
  }
  __syncthreads();                                   /* PR/PF consumed */

  if (w == 0) {                                      /* PO tile over PR region */
#pragma unroll
    for (int c4 = 0; c4 < 16; ++c4)
      *(float4*)&arena[lane * EXS + c4 * 4] =
          make_float4(acc[c4 * 4], acc[c4 * 4 + 1], acc[c4 * 4 + 2], acc[c4 * 4 + 3]);
  }
  __syncthreads();
#pragma unroll
  for (int i = 0; i < 4; ++i) {                      /* PO tile -> out_po */
    const int g = tid + 256 * i, row = g >> 4, c4 = g & 15;
    float4 v = *(const float4*)&arena[row * EXS + c4 * 4];
    *(float4*)(out_po + (size_t)(q0 + row) * CC + c4 * 4) = v;
  }
}

/* K2: masked sums over g arrays using the global n_r from K1. */
__global__ __launch_bounds__(256) void k2_reduce(float* ws) {
  const int nr = (int)ws[WS_CNT];
  const int nf = QTOT - nr;
  float sf = 0.f, sr = 0.f;
  for (int i = blockIdx.x * 256 + threadIdx.x; i < QTOT; i += gridDim.x * 256) {
    if (i < nf) sf += ws[WS_GF + i];
    if (i < nr) sr += ws[WS_GR + i];
  }
#pragma unroll
  for (int off = 32; off > 0; off >>= 1) {
    sf += __shfl_xor(sf, off);
    sr += __shfl_xor(sr, off);
  }
  if ((threadIdx.x & 63) == 0) {
    atomicAdd(&ws[WS_MGF], sf);
    atomicAdd(&ws[WS_MGR], sr);
  }
}

__global__ void k3_final(const float* ws, float* out) {
  if (threadIdx.x == 0) {
    out[0] = ws[WS_MGF] / ws[WS_SCF];
    out[1] = ws[WS_MGR] / ws[WS_SCR];
  }
}

extern "C" void kernel_launch(void* const* d_in, const int* in_sizes, int n_in,
                              void* d_out, int out_size, void* d_ws, size_t ws_size,
                              hipStream_t stream) {
  const float* ctx_r = (const float*)d_in[0];
  const float* ctx_f = (const float*)d_in[1];
  const float* tgt_r = (const float*)d_in[2];
  const float* tgt_f = (const float*)d_in[3];
  float* out = (float*)d_out;
  float* ws = (float*)d_ws;

  k0_norms_zero<<<128, 64, 0, stream>>>(ctx_r, ctx_f, ws);
  k1_main<<<QTOT / QB, BLK, 0, stream>>>(ctx_r, ctx_f, tgt_r, tgt_f, ws, out);
  k2_reduce<<<64, 256, 0, stream>>>(ws);
  k3_final<<<1, 64, 0, stream>>>(ws, out);
}

// Round 3
// 744.556 us; speedup vs baseline: 1.1885x; 1.1885x over previous
//
#include <hip/hip_runtime.h>
#include <math.h>

#define QTOT 65536
#define CC 64
#define DD 512
#define QB 64            /* queries per block */
#define BLK 256
#define NIT 32           /* k-loop iterations, 16 k per iter */
#define EXS 68           /* eArr row stride in floats (272 B, conflict-free) */
#define PS 66            /* staging plane stride in float4s (1056 B) */

/* ws float layout:
   [0] sum c_f  [1] sum c_r  [2] n_r  [3] masked g_f  [4] masked g_r
   [16..144) proto norms (rgb 64 then flow 64)
   [256..256+65536) g_f   [256+65536 ..) g_r  */
enum { WS_SCF = 0, WS_SCR = 1, WS_CNT = 2, WS_MGF = 3, WS_MGR = 4,
       WS_NP = 16, WS_GF = 256, WS_GR = 256 + QTOT };

__global__ __launch_bounds__(64) void k0_norms_zero(
    const float* __restrict__ ctx_r, const float* __restrict__ ctx_f,
    float* ws) {
  const int b = blockIdx.x;        /* 0..127 = modality*64 + proto */
  const int lane = threadIdx.x;
  const float* base = (b < CC) ? ctx_r : ctx_f;
  const int proto = b & (CC - 1);
  const float4* row = (const float4*)(base + (size_t)proto * DD);
  float s = 0.f;
#pragma unroll
  for (int i = 0; i < DD / 4 / 64; ++i) {
    float4 v = row[lane + i * 64];
    s = fmaf(v.x, v.x, s); s = fmaf(v.y, v.y, s);
    s = fmaf(v.z, v.z, s); s = fmaf(v.w, v.w, s);
  }
#pragma unroll
  for (int off = 32; off > 0; off >>= 1) s += __shfl_xor(s, off);
  if (lane == 0) ws[WS_NP + b] = s;
  if (b == 0 && lane < 16) ws[lane] = 0.f;
}

/* K1: wave w = mw*2+ph. mw = modality, ph = proto-half (32 protos/wave).
   lane = query. acc[32]/lane -> no spill at 128-VGPR cap. */
__global__ __launch_bounds__(BLK, 4) void k1_main(
    const float* __restrict__ ctx_r, const float* __restrict__ ctx_f,
    const float* __restrict__ tgt_r, const float* __restrict__ tgt_f,
    float* ws, float* __restrict__ out) {
  /* arena: GEMM staging (2*264 f4 = 8448 B) first, then e-values
     [2*64 rows x 68 floats] = 34816 B. Phases never overlap. */
  __shared__ __align__(16) float arena[2 * QB * EXS];
  __shared__ float xmin[4][QB];    /* reused as KL-partial array later */
  __shared__ float xS[4][QB];
  __shared__ float xT[4][QB];
  __shared__ float xM[4][QB];
  __shared__ float xI[2][QB];

  const int tid = threadIdx.x;
  const int w = tid >> 6;
  const int mw = w >> 1, ph = w & 1;
  const int lane = tid & 63;
  const int q0 = blockIdx.x * QB;

  float acc[32];
#pragma unroll
  for (int c = 0; c < 32; ++c) acc[c] = 0.f;
  float nq = 0.f;

  /* staging loads: thread t -> qr = t>>2, kv = t&3, one f4 per modality */
  const int qr = tid >> 2, kv = tid & 3;
  float4* st = (float4*)arena;
  const float4* gsrc[2] = {(const float4*)tgt_r, (const float4*)tgt_f};
  const size_t gbase = (size_t)(q0 + qr) * 128 + kv;

  float4 pre0 = gsrc[0][gbase];
  float4 pre1 = gsrc[1][gbase];

  const float* Pm = (mw ? ctx_f : ctx_r) + ph * 32 * DD;

#pragma unroll 1
  for (int it = 0; it < NIT; ++it) {
    __syncthreads();
    st[kv * PS + qr] = pre0;
    st[264 + kv * PS + qr] = pre1;
    __syncthreads();
    if (it + 1 < NIT) {
      pre0 = gsrc[0][gbase + (it + 1) * 4];
      pre1 = gsrc[1][gbase + (it + 1) * 4];
    }
    float q_[16];
#pragma unroll
    for (int j = 0; j < 4; ++j) {
      float4 a = st[mw * 264 + j * PS + lane];
      q_[4 * j] = a.x; q_[4 * j + 1] = a.y;
      q_[4 * j + 2] = a.z; q_[4 * j + 3] = a.w;
    }
#pragma unroll
    for (int j = 0; j < 16; ++j) nq = fmaf(q_[j], q_[j], nq);
    const float* P = Pm + it * 16;
#pragma unroll
    for (int c = 0; c < 32; ++c) {
      float a = acc[c];
#pragma unroll
      for (int j = 0; j < 16; ++j) a = fmaf(P[c * DD + j], q_[j], a);
      acc[c] = a;
    }
  }

  /* ---- epilogue ---- */
  __syncthreads();                  /* staging dead; arena becomes eArr */

  const float* np = ws + WS_NP + mw * CC + ph * 32;
  float mloc = 3.4e38f;
#pragma unroll
  for (int c = 0; c < 32; ++c) {
    float d = sqrtf(fmaxf(nq + np[c] - 2.f * acc[c], 0.f));
    acc[c] = d;
    mloc = fminf(mloc, d);
  }
  xmin[w][lane] = mloc;
  __syncthreads();
  const float msh = fminf(fminf(xmin[0][lane], xmin[1][lane]),
                          fminf(xmin[2][lane], xmin[3][lane]));

  float S = 0.f, T = 0.f, M = 0.f;
#pragma unroll
  for (int c = 0; c < 32; ++c) {
    float x = msh - acc[c];
    float e = __expf(x);
    acc[c] = e;                     /* acc now holds e */
    S += e; T = fmaf(e, x, T); M = fmaxf(M, e);
  }
  {
    const int r = (mw * QB + lane) * EXS + ph * 32;
#pragma unroll
    for (int j = 0; j < 8; ++j)
      *(float4*)&arena[r + 4 * j] = make_float4(acc[4 * j], acc[4 * j + 1],
                                                acc[4 * j + 2], acc[4 * j + 3]);
  }
  xS[w][lane] = S; xT[w][lane] = T; xM[w][lane] = M;
  __syncthreads();                  /* B1: eArr + partials visible */

  const float Sr = xS[0][lane] + xS[1][lane];
  const float Sf = xS[2][lane] + xS[3][lane];
  const float Tr = xT[0][lane] + xT[1][lane];
  const float Tf = xT[2][lane] + xT[3][lane];
  const float Mr = fmaxf(xM[0][lane], xM[1][lane]);
  const float Mf = fmaxf(xM[2][lane], xM[3][lane]);
  const float invSr = 1.f / Sr, invSf = 1.f / Sf;
  const float cr = Mr * invSr, cf = Mf * invSf;
  const float hr = __logf(Sr) - Tr * invSr;
  const float hf = __logf(Sf) - Tf * invSf;
  const float wr = cr / (cr + cf), wf = cf / (cr + cf);
  const float dinv = 1.f / (wr * Sr + wf * Sf);

  /* phase A: cross-modality KL partials (+ po for rgb waves) */
  float po[32];
  {
    const int rOpp = ((1 - mw) * QB + lane) * EXS + ph * 32;
    const float invOwn = mw ? invSf : invSr;
    const float invOpp = mw ? invSr : invSf;
    float kl = 0.f;
#pragma unroll
    for (int j = 0; j < 8; ++j) {
      float4 ev = *(const float4*)&arena[rOpp + 4 * j];
#pragma unroll
      for (int u = 0; u < 4; ++u) {
        const int c = 4 * j + u;
        float pOwn = acc[c] * invOwn;
        float pOpp = (&ev.x)[u] * invOpp;
        kl = fmaf(pOwn, __logf(pOwn) - pOpp, kl);
        if (mw == 0)
          po[c] = (wr * acc[c] + wf * (&ev.x)[u]) * dinv;
      }
    }
    xmin[w][lane] = kl;             /* reuse as KL-partial slot */
    if (w == 0) xI[0][lane] = invSr;
    if (w == 2) xI[1][lane] = invSf;
  }
  __syncthreads();                  /* B2 */

  if (w == 0) {
    const float klrf = xmin[0][lane] + xmin[1][lane];
    ws[WS_GR + q0 + lane] = cr * klrf * (1.f / 64.f);
    const float maskv = (hr > hf && cr > cf) ? 1.f : 0.f;
    float scf = cf, scr = cr, scnt = maskv;
#pragma unroll
    for (int off = 32; off > 0; off >>= 1) {
      scf += __shfl_xor(scf, off);
      scr += __shfl_xor(scr, off);
      scnt += __shfl_xor(scnt, off);
    }
    if (lane == 0) {
      atomicAdd(&ws[WS_SCF], scf);
      atomicAdd(&ws[WS_SCR], scr);
      atomicAdd(&ws[WS_CNT], scnt);
    }
  } else if (w == 2) {
    const float klfr = xmin[2][lane] + xmin[3][lane];
    ws[WS_GF + q0 + lane] = cf * klfr * (1.f / 64.f);
  }

  /* cooperative coalesced stores of p_r, p_f from eArr */
  float* out_pf = out + 2;
  float* out_pr = out + 2 + (size_t)QTOT * CC;
  float* out_po = out + 2 + (size_t)2 * QTOT * CC;
#pragma unroll
  for (int i = 0; i < 4; ++i) {
    const int g = tid + 256 * i, row = g >> 4, c4 = g & 15;
    const float sR = xI[0][row], sF = xI[1][row];
    float4 vr = *(const float4*)&arena[row * EXS + c4 * 4];
    float4 vf = *(const float4*)&arena[(QB + row) * EXS + c4 * 4];
    vr.x *= sR; vr.y *= sR; vr.z *= sR; vr.w *= sR;
    vf.x *= sF; vf.y *= sF; vf.z *= sF; vf.w *= sF;
    *(float4*)(out_pr + (size_t)(q0 + row) * CC + c4 * 4) = vr;
    *(float4*)(out_pf + (size_t)(q0 + row) * CC + c4 * 4) = vf;
  }
  __syncthreads();                  /* B3: eArr reads done */

  if (mw == 0) {                    /* stage po over eArr rgb region */
    const int r = lane * EXS + ph * 32;
#pragma unroll
    for (int j = 0; j < 8; ++j)
      *(float4*)&arena[r + 4 * j] = make_float4(po[4 * j], po[4 * j + 1],
                                                po[4 * j + 2], po[4 * j + 3]);
  }
  __syncthreads();                  /* B4 */
#pragma unroll
  for (int i = 0; i < 4; ++i) {
    const int g = tid + 256 * i, row = g >> 4, c4 = g & 15;
    float4 v = *(const float4*)&arena[row * EXS + c4 * 4];
    *(float4*)(out_po + (size_t)(q0 + row) * CC + c4 * 4) = v;
  }
}

/* K2: masked sums over g arrays using the global n_r from K1. */
__global__ __launch_bounds__(256) void k2_reduce(float* ws) {
  const int nr = (int)ws[WS_CNT];
  const int nf = QTOT - nr;
  float sf = 0.f, sr = 0.f;
  for (int i = blockIdx.x * 256 + threadIdx.x; i < QTOT; i += gridDim.x * 256) {
    if (i < nf) sf += ws[WS_GF + i];
    if (i < nr) sr += ws[WS_GR + i];
  }
#pragma unroll
  for (int off = 32; off > 0; off >>= 1) {
    sf += __shfl_xor(sf, off);
    sr += __shfl_xor(sr, off);
  }
  if ((threadIdx.x & 63) == 0) {
    atomicAdd(&ws[WS_MGF], sf);
    atomicAdd(&ws[WS_MGR], sr);
  }
}

__global__ void k3_final(const float* ws, float* out) {
  if (threadIdx.x == 0) {
    out[0] = ws[WS_MGF] / ws[WS_SCF];
    out[1] = ws[WS_MGR] / ws[WS_SCR];
  }
}

extern "C" void kernel_launch(void* const* d_in, const int* in_sizes, int n_in,
                              void* d_out, int out_size, void* d_ws, size_t ws_size,
                              hipStream_t stream) {
  const float* ctx_r = (const float*)d_in[0];
  const float* ctx_f = (const float*)d_in[1];
  const float* tgt_r = (const float*)d_in[2];
  const float* tgt_f = (const float*)d_in[3];
  float* out = (float*)d_out;
  float* ws = (float*)d_ws;

  k0_norms_zero<<<128, 64, 0, stream>>>(ctx_r, ctx_f, ws);
  k1_main<<<QTOT / QB, BLK, 0, stream>>>(ctx_r, ctx_f, tgt_r, tgt_f, ws, out);
  k2_reduce<<<64, 256, 0, stream>>>(ws);
  k3_final<<<1, 64, 0, stream>>>(ws, out);
}

// Round 4
// 368.461 us; speedup vs baseline: 2.4015x; 2.0207x over previous
//
#include <hip/hip_runtime.h>
#include <math.h>

#define QTOT 65536
#define CC 64
#define DD 512
#define QB 64            /* queries per block */
#define BLK 256
#define NIT 16           /* K-chunks of 32 */
#define EXS 68           /* dots/e-value row stride in floats (272 B) */
#define ASTR 40          /* A-staging row stride in f16 (80 B) */

typedef _Float16 half8 __attribute__((ext_vector_type(8)));
typedef float floatx4 __attribute__((ext_vector_type(4)));

/* ws float layout:
   [0] sum c_f  [1] sum c_r  [2] n_r  [3] masked g_f  [4] masked g_r
   [16..144) proto norms (rgb 64 then flow 64)
   [256..256+65536) g_f   [256+65536..) g_r
   [256+2*65536 ..) f16 protos, frag order: [mod][s][p][kk], 32768 halfs/mod */
enum { WS_SCF = 0, WS_SCR = 1, WS_CNT = 2, WS_MGF = 3, WS_MGR = 4,
       WS_NP = 16, WS_GF = 256, WS_GR = 256 + QTOT, WS_PH = 256 + 2 * QTOT };

/* K0: proto norms (fp32) + f16 fragment-order conversion + zero scalars. */
__global__ __launch_bounds__(64) void k0_prep(
    const float* __restrict__ ctx_r, const float* __restrict__ ctx_f,
    float* ws) {
  const int b = blockIdx.x;        /* 0..127 = mod*64 + proto */
  const int lane = threadIdx.x;
  const int m = b >> 6, p = b & 63;
  const float* row = ((m == 0) ? ctx_r : ctx_f) + (size_t)p * DD;
  const float4* r4 = (const float4*)row;
  float s = 0.f;
#pragma unroll
  for (int i = 0; i < 2; ++i) {
    float4 v = r4[lane + i * 64];
    s = fmaf(v.x, v.x, s); s = fmaf(v.y, v.y, s);
    s = fmaf(v.z, v.z, s); s = fmaf(v.w, v.w, s);
  }
#pragma unroll
  for (int off = 32; off > 0; off >>= 1) s += __shfl_xor(s, off);
  if (lane == 0) ws[WS_NP + b] = s;
  if (b == 0 && lane < 16) ws[lane] = 0.f;

  /* f16 conversion: lane handles k = lane*8 .. +8 -> [s=lane>>2][p][kk=(lane&3)*8] */
  _Float16* hF = (_Float16*)(ws + WS_PH);
  float4 a = r4[lane * 2], c = r4[lane * 2 + 1];
  half8 h;
  h[0] = (_Float16)a.x; h[1] = (_Float16)a.y; h[2] = (_Float16)a.z; h[3] = (_Float16)a.w;
  h[4] = (_Float16)c.x; h[5] = (_Float16)c.y; h[6] = (_Float16)c.z; h[7] = (_Float16)c.w;
  *(half8*)&hF[m * 32768 + (lane >> 2) * 2048 + p * 32 + (lane & 3) * 8] = h;
}

/* K1: wave w = mw*2+qh (modality, query-half). MFMA 16x16x32 f16.
   Wave computes 32q x 64p. Dots transposed via LDS to R3's lane-per-query
   epilogue (verified C-layout col=lane&15, row=quad*4+reg). */
__global__ __launch_bounds__(BLK, 4) void k1_main(
    const float* __restrict__ tgt_r, const float* __restrict__ tgt_f,
    float* ws, float* __restrict__ out) {
  __shared__ __align__(16) float arena[2 * QB * EXS];  /* 34816 B, phase-reused */
  __shared__ float xmin[4][QB];
  __shared__ float xS[4][QB];
  __shared__ float xT[4][QB];
  __shared__ float xM[4][QB];
  __shared__ float xI[2][QB];
  __shared__ float nqA[2][QB];

  const int tid = threadIdx.x;
  const int w = tid >> 6, lane = tid & 63;
  const int mw = w >> 1, qh = w & 1;
  const int col = lane & 15, quad = lane >> 4;
  const int q0 = blockIdx.x * QB;

  _Float16* As = (_Float16*)arena;              /* [mod][64][ASTR] f16 */
  const _Float16* hF = (const _Float16*)(ws + WS_PH);

  floatx4 acc[2][4];
#pragma unroll
  for (int t = 0; t < 2; ++t)
#pragma unroll
    for (int u = 0; u < 4; ++u) acc[t][u] = (floatx4){0.f, 0.f, 0.f, 0.f};

  /* staging: thread t -> q-row qr=t>>2, k-quarter kv=t&3 (8 floats/mod/iter) */
  const int qr = tid >> 2, kv = tid & 3;
  const float4* g0 = (const float4*)(tgt_r + (size_t)(q0 + qr) * DD) + kv * 2;
  const float4* g1 = (const float4*)(tgt_f + (size_t)(q0 + qr) * DD) + kv * 2;
  float nq0 = 0.f, nq1 = 0.f;
  float4 p00 = g0[0], p01 = g0[1], p10 = g1[0], p11 = g1[1];

#pragma unroll 1
  for (int it = 0; it < NIT; ++it) {
    __syncthreads();
    half8 h0, h1;
    h0[0] = (_Float16)p00.x; h0[1] = (_Float16)p00.y; h0[2] = (_Float16)p00.z; h0[3] = (_Float16)p00.w;
    h0[4] = (_Float16)p01.x; h0[5] = (_Float16)p01.y; h0[6] = (_Float16)p01.z; h0[7] = (_Float16)p01.w;
    h1[0] = (_Float16)p10.x; h1[1] = (_Float16)p10.y; h1[2] = (_Float16)p10.z; h1[3] = (_Float16)p10.w;
    h1[4] = (_Float16)p11.x; h1[5] = (_Float16)p11.y; h1[6] = (_Float16)p11.z; h1[7] = (_Float16)p11.w;
    *(half8*)&As[qr * ASTR + kv * 8] = h0;
    *(half8*)&As[64 * ASTR + qr * ASTR + kv * 8] = h1;
    nq0 = fmaf(p00.x, p00.x, nq0); nq0 = fmaf(p00.y, p00.y, nq0);
    nq0 = fmaf(p00.z, p00.z, nq0); nq0 = fmaf(p00.w, p00.w, nq0);
    nq0 = fmaf(p01.x, p01.x, nq0); nq0 = fmaf(p01.y, p01.y, nq0);
    nq0 = fmaf(p01.z, p01.z, nq0); nq0 = fmaf(p01.w, p01.w, nq0);
    nq1 = fmaf(p10.x, p10.x, nq1); nq1 = fmaf(p10.y, p10.y, nq1);
    nq1 = fmaf(p10.z, p10.z, nq1); nq1 = fmaf(p10.w, p10.w, nq1);
    nq1 = fmaf(p11.x, p11.x, nq1); nq1 = fmaf(p11.y, p11.y, nq1);
    nq1 = fmaf(p11.z, p11.z, nq1); nq1 = fmaf(p11.w, p11.w, nq1);
    __syncthreads();
    if (it + 1 < NIT) {
      p00 = g0[(it + 1) * 8]; p01 = g0[(it + 1) * 8 + 1];
      p10 = g1[(it + 1) * 8]; p11 = g1[(it + 1) * 8 + 1];
    }
    half8 afr[2];
#pragma unroll
    for (int t = 0; t < 2; ++t)
      afr[t] = *(const half8*)&As[mw * 64 * ASTR + (qh * 32 + t * 16 + col) * ASTR + quad * 8];
    const _Float16* bb = hF + mw * 32768 + it * 2048 + col * 32 + quad * 8;
#pragma unroll
    for (int u = 0; u < 4; ++u) {
      half8 bfr = *(const half8*)&bb[u * 512];
#pragma unroll
      for (int t = 0; t < 2; ++t)
        acc[t][u] = __builtin_amdgcn_mfma_f32_16x16x32_f16(afr[t], bfr, acc[t][u], 0, 0, 0);
    }
  }

  /* query-norm combine (4 adjacent lanes per q-row) */
  nq0 += __shfl_xor(nq0, 1); nq0 += __shfl_xor(nq0, 2);
  nq1 += __shfl_xor(nq1, 1); nq1 += __shfl_xor(nq1, 2);
  if (kv == 0) { nqA[0][qr] = nq0; nqA[1][qr] = nq1; }

  /* transpose dots: C-layout -> [mod*64+q][p] rows in arena */
  __syncthreads();                  /* staging dead */
#pragma unroll
  for (int t = 0; t < 2; ++t)
#pragma unroll
    for (int u = 0; u < 4; ++u)
#pragma unroll
      for (int j = 0; j < 4; ++j) {
        const int qg = qh * 32 + t * 16 + quad * 4 + j;
        arena[(mw * QB + qg) * EXS + u * 16 + col] = acc[t][u][j];
      }
  __syncthreads();

  /* ---- R3 epilogue: wave = (mwE, phE), lane = query ---- */
  const int mwE = mw, phE = qh;
  float acc2[32];
#pragma unroll
  for (int j = 0; j < 8; ++j) {
    float4 v = *(const float4*)&arena[(mwE * QB + lane) * EXS + phE * 32 + j * 4];
    acc2[4 * j] = v.x; acc2[4 * j + 1] = v.y; acc2[4 * j + 2] = v.z; acc2[4 * j + 3] = v.w;
  }
  const float nq = nqA[mwE][lane];
  const float* np = ws + WS_NP + mwE * CC + phE * 32;
  float mloc = 3.4e38f;
#pragma unroll
  for (int c = 0; c < 32; ++c) {
    float d = sqrtf(fmaxf(nq + np[c] - 2.f * acc2[c], 0.f));
    acc2[c] = d;
    mloc = fminf(mloc, d);
  }
  xmin[w][lane] = mloc;
  __syncthreads();
  const float msh = fminf(fminf(xmin[0][lane], xmin[1][lane]),
                          fminf(xmin[2][lane], xmin[3][lane]));

  float S = 0.f, T = 0.f, M = 0.f;
#pragma unroll
  for (int c = 0; c < 32; ++c) {
    float x = msh - acc2[c];
    float e = __expf(x);
    acc2[c] = e;
    S += e; T = fmaf(e, x, T); M = fmaxf(M, e);
  }
  {
    const int r = (mwE * QB + lane) * EXS + phE * 32;
#pragma unroll
    for (int j = 0; j < 8; ++j)
      *(float4*)&arena[r + 4 * j] = make_float4(acc2[4 * j], acc2[4 * j + 1],
                                                acc2[4 * j + 2], acc2[4 * j + 3]);
  }
  xS[w][lane] = S; xT[w][lane] = T; xM[w][lane] = M;
  __syncthreads();                  /* B1 */

  const float Sr = xS[0][lane] + xS[1][lane];
  const float Sf = xS[2][lane] + xS[3][lane];
  const float Tr = xT[0][lane] + xT[1][lane];
  const float Tf = xT[2][lane] + xT[3][lane];
  const float Mr = fmaxf(xM[0][lane], xM[1][lane]);
  const float Mf = fmaxf(xM[2][lane], xM[3][lane]);
  const float invSr = 1.f / Sr, invSf = 1.f / Sf;
  const float cr = Mr * invSr, cf = Mf * invSf;
  const float hr = __logf(Sr) - Tr * invSr;
  const float hf = __logf(Sf) - Tf * invSf;
  const float wr = cr / (cr + cf), wf = cf / (cr + cf);
  const float dinv = 1.f / (wr * Sr + wf * Sf);

  float po[32];
  {
    const int rOpp = ((1 - mwE) * QB + lane) * EXS + phE * 32;
    const float invOwn = mwE ? invSf : invSr;
    const float invOpp = mwE ? invSr : invSf;
    float kl = 0.f;
#pragma unroll
    for (int j = 0; j < 8; ++j) {
      float4 ev = *(const float4*)&arena[rOpp + 4 * j];
#pragma unroll
      for (int u = 0; u < 4; ++u) {
        const int c = 4 * j + u;
        float pOwn = acc2[c] * invOwn;
        float pOpp = (&ev.x)[u] * invOpp;
        kl = fmaf(pOwn, __logf(pOwn) - pOpp, kl);
        if (mwE == 0)
          po[c] = (wr * acc2[c] + wf * (&ev.x)[u]) * dinv;
      }
    }
    xmin[w][lane] = kl;
    if (w == 0) xI[0][lane] = invSr;
    if (w == 2) xI[1][lane] = invSf;
  }
  __syncthreads();                  /* B2 */

  if (w == 0) {
    const float klrf = xmin[0][lane] + xmin[1][lane];
    ws[WS_GR + q0 + lane] = cr * klrf * (1.f / 64.f);
    const float maskv = (hr > hf && cr > cf) ? 1.f : 0.f;
    float scf = cf, scr = cr, scnt = maskv;
#pragma unroll
    for (int off = 32; off > 0; off >>= 1) {
      scf += __shfl_xor(scf, off);
      scr += __shfl_xor(scr, off);
      scnt += __shfl_xor(scnt, off);
    }
    if (lane == 0) {
      atomicAdd(&ws[WS_SCF], scf);
      atomicAdd(&ws[WS_SCR], scr);
      atomicAdd(&ws[WS_CNT], scnt);
    }
  } else if (w == 2) {
    const float klfr = xmin[2][lane] + xmin[3][lane];
    ws[WS_GF + q0 + lane] = cf * klfr * (1.f / 64.f);
  }

  float* out_pf = out + 2;
  float* out_pr = out + 2 + (size_t)QTOT * CC;
  float* out_po = out + 2 + (size_t)2 * QTOT * CC;
#pragma unroll
  for (int i = 0; i < 4; ++i) {
    const int g = tid + 256 * i, row = g >> 4, c4 = g & 15;
    const float sR = xI[0][row], sF = xI[1][row];
    float4 vr = *(const float4*)&arena[row * EXS + c4 * 4];
    float4 vf = *(const float4*)&arena[(QB + row) * EXS + c4 * 4];
    vr.x *= sR; vr.y *= sR; vr.z *= sR; vr.w *= sR;
    vf.x *= sF; vf.y *= sF; vf.z *= sF; vf.w *= sF;
    *(float4*)(out_pr + (size_t)(q0 + row) * CC + c4 * 4) = vr;
    *(float4*)(out_pf + (size_t)(q0 + row) * CC + c4 * 4) = vf;
  }
  __syncthreads();                  /* B3 */

  if (mwE == 0) {
    const int r = lane * EXS + phE * 32;
#pragma unroll
    for (int j = 0; j < 8; ++j)
      *(float4*)&arena[r + 4 * j] = make_float4(po[4 * j], po[4 * j + 1],
                                                po[4 * j + 2], po[4 * j + 3]);
  }
  __syncthreads();                  /* B4 */
#pragma unroll
  for (int i = 0; i < 4; ++i) {
    const int g = tid + 256 * i, row = g >> 4, c4 = g & 15;
    float4 v = *(const float4*)&arena[row * EXS + c4 * 4];
    *(float4*)(out_po + (size_t)(q0 + row) * CC + c4 * 4) = v;
  }
}

/* K2: masked sums over g arrays using the global n_r from K1. */
__global__ __launch_bounds__(256) void k2_reduce(float* ws) {
  const int nr = (int)ws[WS_CNT];
  const int nf = QTOT - nr;
  float sf = 0.f, sr = 0.f;
  for (int i = blockIdx.x * 256 + threadIdx.x; i < QTOT; i += gridDim.x * 256) {
    if (i < nf) sf += ws[WS_GF + i];
    if (i < nr) sr += ws[WS_GR + i];
  }
#pragma unroll
  for (int off = 32; off > 0; off >>= 1) {
    sf += __shfl_xor(sf, off);
    sr += __shfl_xor(sr, off);
  }
  if ((threadIdx.x & 63) == 0) {
    atomicAdd(&ws[WS_MGF], sf);
    atomicAdd(&ws[WS_MGR], sr);
  }
}

__global__ void k3_final(const float* ws, float* out) {
  if (threadIdx.x == 0) {
    out[0] = ws[WS_MGF] / ws[WS_SCF];
    out[1] = ws[WS_MGR] / ws[WS_SCR];
  }
}

extern "C" void kernel_launch(void* const* d_in, const int* in_sizes, int n_in,
                              void* d_out, int out_size, void* d_ws, size_t ws_size,
                              hipStream_t stream) {
  const float* ctx_r = (const float*)d_in[0];
  const float* ctx_f = (const float*)d_in[1];
  const float* tgt_r = (const float*)d_in[2];
  const float* tgt_f = (const float*)d_in[3];
  float* out = (float*)d_out;
  float* ws = (float*)d_ws;

  k0_prep<<<128, 64, 0, stream>>>(ctx_r, ctx_f, ws);
  k1_main<<<QTOT / QB, BLK, 0, stream>>>(tgt_r, tgt_f, ws, out);
  k2_reduce<<<64, 256, 0, stream>>>(ws);
  k3_final<<<1, 64, 0, stream>>>(ws, out);
}